// Round 1
// baseline (74.271 us; speedup 1.0000x reference)
//
#include <hip/hip_runtime.h>

#define NPIX 16384
#define WIDTH 128

// ---------------------------------------------------------------------------
// Kernel 1: depth -> point cloud (x, y, z, |p|^2 [+1e30 if invalid]) for both
// target (pcT) and pred (pcP), plus valid mask (1.0/0.0) from target>0.
// ---------------------------------------------------------------------------
__global__ __launch_bounds__(256) void pc_precompute_kernel(
    const float* __restrict__ pred,
    const float* __restrict__ target,
    const float* __restrict__ P,
    float4* __restrict__ pcT,
    float4* __restrict__ pcP,
    float* __restrict__ validArr) {
    int p = blockIdx.x * blockDim.x + threadIdx.x;
    if (p >= NPIX) return;
    float fu  = P[0];
    float cu  = P[2];
    float p03 = P[3];
    float fv  = P[5];
    float cv  = P[6];
    float p13 = P[7];
    float p23 = P[11];

    float px = (float)(p & (WIDTH - 1));
    float py = (float)(p >> 7);

    float dt = target[p];
    float dp = pred[p];

    bool ok = (dt > 0.0f);
    float inf_add = ok ? 0.0f : 1e30f;

    // target cloud (pc1)
    float xt = (px * (dt + p23) - (cu * dt + p03)) / fu;
    float yt = (py * (dt + p23) - (cv * dt + p13)) / fv;
    float st = xt * xt + yt * yt + dt * dt;
    pcT[p] = make_float4(xt, yt, dt, st + inf_add);

    // pred cloud (pc2)
    float xp = (px * (dp + p23) - (cu * dp + p03)) / fu;
    float yp = (py * (dp + p23) - (cv * dp + p13)) / fv;
    float sp = xp * xp + yp * yp + dp * dp;
    pcP[p] = make_float4(xp, yp, dp, sp + inf_add);

    validArr[p] = ok ? 1.0f : 0.0f;
}

// ---------------------------------------------------------------------------
// Kernel 2: tiled pairwise min. Each block: 1024 A-points (4/thread in regs),
// one J-slice of B staged through LDS in 256-point tiles. blockIdx.z selects
// direction (0: A=pcT,B=pcP -> pm12 ; 1: A=pcP,B=pcT -> pm21).
// d(i,j) = wA + wB - 2*dot(a,b); invalid B has +1e30 baked into wB.
// ---------------------------------------------------------------------------
__global__ __launch_bounds__(256) void pair_min_kernel(
    const float4* __restrict__ pcT,
    const float4* __restrict__ pcP,
    float* __restrict__ pm12,
    float* __restrict__ pm21,
    int jlen) {
    const float4* __restrict__ A;
    const float4* __restrict__ B;
    float* __restrict__ pm;
    if (blockIdx.z == 0) { A = pcT; B = pcP; pm = pm12; }
    else                 { A = pcP; B = pcT; pm = pm21; }

    __shared__ float4 sB[256];
    int t = threadIdx.x;
    int abase = blockIdx.x * 1024 + t;
    int jbase = blockIdx.y * jlen;

    float4 a0 = A[abase];
    float4 a1 = A[abase + 256];
    float4 a2 = A[abase + 512];
    float4 a3 = A[abase + 768];

    float m0 = 3e38f, m1 = 3e38f, m2 = 3e38f, m3 = 3e38f;

    for (int jt = 0; jt < jlen; jt += 256) {
        __syncthreads();
        sB[t] = B[jbase + jt + t];
        __syncthreads();
        #pragma unroll 4
        for (int j = 0; j < 256; ++j) {
            float4 b = sB[j];
            float d0 = fmaf(-2.0f, fmaf(a0.x, b.x, fmaf(a0.y, b.y, a0.z * b.z)), a0.w + b.w);
            float d1 = fmaf(-2.0f, fmaf(a1.x, b.x, fmaf(a1.y, b.y, a1.z * b.z)), a1.w + b.w);
            float d2 = fmaf(-2.0f, fmaf(a2.x, b.x, fmaf(a2.y, b.y, a2.z * b.z)), a2.w + b.w);
            float d3 = fmaf(-2.0f, fmaf(a3.x, b.x, fmaf(a3.y, b.y, a3.z * b.z)), a3.w + b.w);
            m0 = fminf(m0, d0);
            m1 = fminf(m1, d1);
            m2 = fminf(m2, d2);
            m3 = fminf(m3, d3);
        }
    }

    int obase = blockIdx.y * NPIX + abase;
    pm[obase]       = m0;
    pm[obase + 256] = m1;
    pm[obase + 512] = m2;
    pm[obase + 768] = m3;
}

// ---------------------------------------------------------------------------
// Kernel 3: per-pixel combine of J-slice partial mins, masked sum-reduce to
// per-block partials (deterministic, no float atomics).
// ---------------------------------------------------------------------------
__global__ __launch_bounds__(256) void reduce_kernel(
    const float* __restrict__ pm12,
    const float* __restrict__ pm21,
    const float* __restrict__ validArr,
    int JC,
    float* __restrict__ bsum,
    float* __restrict__ bn) {
    int a = blockIdx.x * 256 + threadIdx.x;
    float m12 = 3e38f, m21 = 3e38f;
    for (int jc = 0; jc < JC; ++jc) {
        m12 = fminf(m12, pm12[jc * NPIX + a]);
        m21 = fminf(m21, pm21[jc * NPIX + a]);
    }
    float v = validArr[a];
    float contrib = v * (m12 + m21);

    // 64-lane wave reduce
    for (int o = 32; o > 0; o >>= 1) {
        contrib += __shfl_down(contrib, o);
        v += __shfl_down(v, o);
    }
    __shared__ float ls[8];
    int wid = threadIdx.x >> 6;
    int lane = threadIdx.x & 63;
    if (lane == 0) { ls[wid] = contrib; ls[wid + 4] = v; }
    __syncthreads();
    if (threadIdx.x == 0) {
        bsum[blockIdx.x] = (ls[0] + ls[1]) + (ls[2] + ls[3]);
        bn[blockIdx.x]   = (ls[4] + ls[5]) + (ls[6] + ls[7]);
    }
}

// ---------------------------------------------------------------------------
// Kernel 4: final fixed-order sum + divide.
// ---------------------------------------------------------------------------
__global__ void final_kernel(const float* __restrict__ bsum,
                             const float* __restrict__ bn,
                             float* __restrict__ out) {
    if (threadIdx.x == 0) {
        float s = 0.0f, n = 0.0f;
        for (int i = 0; i < 64; ++i) { s += bsum[i]; n += bn[i]; }
        out[0] = s / n;
    }
}

extern "C" void kernel_launch(void* const* d_in, const int* in_sizes, int n_in,
                              void* d_out, int out_size, void* d_ws, size_t ws_size,
                              hipStream_t stream) {
    const float* pred   = (const float*)d_in[0];
    const float* target = (const float*)d_in[1];
    const float* P      = (const float*)d_in[2];
    float* out = (float*)d_out;

    char* ws = (char*)d_ws;
    float4* pcT   = (float4*)ws;                      // NPIX float4
    float4* pcP   = (float4*)(ws + (size_t)NPIX * 16);
    float*  valid = (float*)(ws + (size_t)NPIX * 32); // NPIX floats
    size_t base = (size_t)NPIX * 36;

    // choose J-chunk count that fits the workspace (deterministic given ws_size)
    int JC = 16;
    while (JC > 1 && base + (size_t)2 * JC * NPIX * 4 + 512 > ws_size) JC >>= 1;

    float* pm12 = (float*)(ws + base);
    float* pm21 = pm12 + (size_t)JC * NPIX;
    float* bsum = pm21 + (size_t)JC * NPIX;
    float* bn   = bsum + 64;

    pc_precompute_kernel<<<dim3(NPIX / 256), 256, 0, stream>>>(pred, target, P, pcT, pcP, valid);

    int jlen = NPIX / JC;
    dim3 grid(NPIX / 1024, JC, 2);
    pair_min_kernel<<<grid, 256, 0, stream>>>(pcT, pcP, pm12, pm21, jlen);

    reduce_kernel<<<dim3(NPIX / 256), 256, 0, stream>>>(pm12, pm21, valid, JC, bsum, bn);
    final_kernel<<<1, 64, 0, stream>>>(bsum, bn, out);
}

// Round 2
// 73.829 us; speedup vs baseline: 1.0060x; 1.0060x over previous
//
#include <hip/hip_runtime.h>

#define NPIX 16384
#define WIDTH 128

// ---------------------------------------------------------------------------
// Kernel 1: depth -> point cloud (x, y, z, |p|^2 [+1e30 if invalid]) for both
// target (pcT) and pred (pcP), plus valid mask (1.0/0.0) from target>0.
// The +1e30 on .w implements the B-side valid mask (masked pairs lose the min).
// ---------------------------------------------------------------------------
__global__ __launch_bounds__(256) void pc_precompute_kernel(
    const float* __restrict__ pred,
    const float* __restrict__ target,
    const float* __restrict__ P,
    float4* __restrict__ pcT,
    float4* __restrict__ pcP,
    float* __restrict__ validArr) {
    int p = blockIdx.x * blockDim.x + threadIdx.x;
    if (p >= NPIX) return;
    float fu  = P[0];
    float cu  = P[2];
    float p03 = P[3];
    float fv  = P[5];
    float cv  = P[6];
    float p13 = P[7];
    float p23 = P[11];

    float px = (float)(p & (WIDTH - 1));
    float py = (float)(p >> 7);

    float dt = target[p];
    float dp = pred[p];

    bool ok = (dt > 0.0f);
    float inf_add = ok ? 0.0f : 1e30f;

    // target cloud (pc1)
    float xt = (px * (dt + p23) - (cu * dt + p03)) / fu;
    float yt = (py * (dt + p23) - (cv * dt + p13)) / fv;
    float st = xt * xt + yt * yt + dt * dt;
    pcT[p] = make_float4(xt, yt, dt, st + inf_add);

    // pred cloud (pc2)
    float xp = (px * (dp + p23) - (cu * dp + p03)) / fu;
    float yp = (py * (dp + p23) - (cv * dp + p13)) / fv;
    float sp = xp * xp + yp * yp + dp * dp;
    pcP[p] = make_float4(xp, yp, dp, sp + inf_add);

    validArr[p] = ok ? 1.0f : 0.0f;
}

// ---------------------------------------------------------------------------
// Kernel 2: tiled pairwise min. Each block: 1024 A-points (4/thread in regs),
// one J-slice of B staged through LDS (256-point tiles, broadcast reads).
// blockIdx.z selects direction (0: A=pcT,B=pcP -> pm12 ; 1: A=pcP,B=pcT).
// Inner loop computes e = (-2a)·b + |b|^2 (3 FMA) and a running min (|a|^2 is
// added back in the reduce kernel). Invalid B has +1e30 baked into b.w.
// ---------------------------------------------------------------------------
__global__ __launch_bounds__(256, 4) void pair_min_kernel(
    const float4* __restrict__ pcT,
    const float4* __restrict__ pcP,
    float* __restrict__ pm12,
    float* __restrict__ pm21,
    int jlen) {
    const float4* __restrict__ A;
    const float4* __restrict__ B;
    float* __restrict__ pm;
    if (blockIdx.z == 0) { A = pcT; B = pcP; pm = pm12; }
    else                 { A = pcP; B = pcT; pm = pm21; }

    __shared__ float4 sB[256];
    int t = threadIdx.x;
    int abase = blockIdx.x * 1024 + t;
    int jbase = blockIdx.y * jlen;

    float4 a0 = A[abase];
    float4 a1 = A[abase + 256];
    float4 a2 = A[abase + 512];
    float4 a3 = A[abase + 768];
    // fold -2 into A registers (|a|^2 handled in reduce kernel)
    float a0x = -2.0f * a0.x, a0y = -2.0f * a0.y, a0z = -2.0f * a0.z;
    float a1x = -2.0f * a1.x, a1y = -2.0f * a1.y, a1z = -2.0f * a1.z;
    float a2x = -2.0f * a2.x, a2y = -2.0f * a2.y, a2z = -2.0f * a2.z;
    float a3x = -2.0f * a3.x, a3y = -2.0f * a3.y, a3z = -2.0f * a3.z;

    float m0 = 3e38f, m1 = 3e38f, m2 = 3e38f, m3 = 3e38f;

    for (int jt = 0; jt < jlen; jt += 256) {
        __syncthreads();
        sB[t] = B[jbase + jt + t];
        __syncthreads();
        #pragma unroll 2
        for (int j = 0; j < 256; j += 2) {
            float4 b  = sB[j];
            float4 b2 = sB[j + 1];
            float e00 = fmaf(a0x, b.x,  fmaf(a0y, b.y,  fmaf(a0z, b.z,  b.w)));
            float e10 = fmaf(a1x, b.x,  fmaf(a1y, b.y,  fmaf(a1z, b.z,  b.w)));
            float e20 = fmaf(a2x, b.x,  fmaf(a2y, b.y,  fmaf(a2z, b.z,  b.w)));
            float e30 = fmaf(a3x, b.x,  fmaf(a3y, b.y,  fmaf(a3z, b.z,  b.w)));
            float e01 = fmaf(a0x, b2.x, fmaf(a0y, b2.y, fmaf(a0z, b2.z, b2.w)));
            float e11 = fmaf(a1x, b2.x, fmaf(a1y, b2.y, fmaf(a1z, b2.z, b2.w)));
            float e21 = fmaf(a2x, b2.x, fmaf(a2y, b2.y, fmaf(a2z, b2.z, b2.w)));
            float e31 = fmaf(a3x, b2.x, fmaf(a3y, b2.y, fmaf(a3z, b2.z, b2.w)));
            m0 = fminf(m0, fminf(e00, e01));
            m1 = fminf(m1, fminf(e10, e11));
            m2 = fminf(m2, fminf(e20, e21));
            m3 = fminf(m3, fminf(e30, e31));
        }
    }

    int obase = blockIdx.y * NPIX + abase;
    pm[obase]       = m0;
    pm[obase + 256] = m1;
    pm[obase + 512] = m2;
    pm[obase + 768] = m3;
}

// ---------------------------------------------------------------------------
// Kernel 3: per-pixel combine of J-slice partial mins (+|a|^2 add-back),
// masked sum-reduce to per-block partials (deterministic, no float atomics).
// ---------------------------------------------------------------------------
__global__ __launch_bounds__(256) void reduce_kernel(
    const float* __restrict__ pm12,
    const float* __restrict__ pm21,
    const float4* __restrict__ pcT,
    const float4* __restrict__ pcP,
    const float* __restrict__ validArr,
    int JC,
    float* __restrict__ bsum,
    float* __restrict__ bn) {
    int a = blockIdx.x * 256 + threadIdx.x;
    float m12 = 3e38f, m21 = 3e38f;
    for (int jc = 0; jc < JC; ++jc) {
        m12 = fminf(m12, pm12[jc * NPIX + a]);
        m21 = fminf(m21, pm21[jc * NPIX + a]);
    }
    float v = validArr[a];
    // add back |a|^2 for each direction (A=pcT for 12, A=pcP for 21).
    // For invalid pixels .w contains +1e30 but v==0 masks the contribution.
    float dist12 = m12 + pcT[a].w;
    float dist21 = m21 + pcP[a].w;
    float contrib = v * (dist12 + dist21);

    // 64-lane wave reduce
    for (int o = 32; o > 0; o >>= 1) {
        contrib += __shfl_down(contrib, o);
        v += __shfl_down(v, o);
    }
    __shared__ float ls[8];
    int wid = threadIdx.x >> 6;
    int lane = threadIdx.x & 63;
    if (lane == 0) { ls[wid] = contrib; ls[wid + 4] = v; }
    __syncthreads();
    if (threadIdx.x == 0) {
        bsum[blockIdx.x] = (ls[0] + ls[1]) + (ls[2] + ls[3]);
        bn[blockIdx.x]   = (ls[4] + ls[5]) + (ls[6] + ls[7]);
    }
}

// ---------------------------------------------------------------------------
// Kernel 4: final fixed-order sum + divide.
// ---------------------------------------------------------------------------
__global__ void final_kernel(const float* __restrict__ bsum,
                             const float* __restrict__ bn,
                             float* __restrict__ out) {
    if (threadIdx.x == 0) {
        float s = 0.0f, n = 0.0f;
        for (int i = 0; i < 64; ++i) { s += bsum[i]; n += bn[i]; }
        out[0] = s / n;
    }
}

extern "C" void kernel_launch(void* const* d_in, const int* in_sizes, int n_in,
                              void* d_out, int out_size, void* d_ws, size_t ws_size,
                              hipStream_t stream) {
    const float* pred   = (const float*)d_in[0];
    const float* target = (const float*)d_in[1];
    const float* P      = (const float*)d_in[2];
    float* out = (float*)d_out;

    char* ws = (char*)d_ws;
    float4* pcT   = (float4*)ws;                      // NPIX float4
    float4* pcP   = (float4*)(ws + (size_t)NPIX * 16);
    float*  valid = (float*)(ws + (size_t)NPIX * 32); // NPIX floats
    size_t base = (size_t)NPIX * 36;

    // choose J-chunk count that fits the workspace (deterministic given ws_size)
    int JC = 64;
    while (JC > 1 && base + (size_t)2 * JC * NPIX * 4 + 512 > ws_size) JC >>= 1;

    float* pm12 = (float*)(ws + base);
    float* pm21 = pm12 + (size_t)JC * NPIX;
    float* bsum = pm21 + (size_t)JC * NPIX;
    float* bn   = bsum + 64;

    pc_precompute_kernel<<<dim3(NPIX / 256), 256, 0, stream>>>(pred, target, P, pcT, pcP, valid);

    int jlen = NPIX / JC;
    dim3 grid(NPIX / 1024, JC, 2);
    pair_min_kernel<<<grid, 256, 0, stream>>>(pcT, pcP, pm12, pm21, jlen);

    reduce_kernel<<<dim3(NPIX / 256), 256, 0, stream>>>(pm12, pm21, pcT, pcP, valid, JC, bsum, bn);
    final_kernel<<<1, 64, 0, stream>>>(bsum, bn, out);
}

// Round 3
// 54.848 us; speedup vs baseline: 1.3541x; 1.3461x over previous
//
#include <hip/hip_runtime.h>

#define NPIX 16384
#define WIDTH 128
#define JC 64            // number of j-slices (tiles)
#define JLEN (NPIX / JC) // 256 B-points per tile == blockDim
#define APT 8            // A-points per thread
#define ABLK (256 * APT) // 2048 A-points per block

// depth -> (x, y, z, |p|^2 + inf_add). Same math as reference pixel2xyz.
__device__ __forceinline__ float4 make_point(float d, int p,
    float fu, float cu, float p03, float fv, float cv, float p13, float p23,
    float inf_add) {
    float px = (float)(p & (WIDTH - 1));
    float py = (float)(p >> 7);
    float x = (px * (d + p23) - (cu * d + p03)) / fu;
    float y = (py * (d + p23) - (cv * d + p13)) / fv;
    float s = x * x + y * y + d * d;
    return make_float4(x, y, d, s + inf_add);
}

// ---------------------------------------------------------------------------
// Pairwise-min kernel (precompute fused). Each block: 2048 A-points
// (8/thread in regs, -2x folded), one 256-point B tile in LDS (broadcast
// reads). blockIdx.z picks direction. Inner op: e = (-2a)·b + |b|^2
// (3 FMA) + running min3; |a|^2 added back in reduce. Invalid pixels
// (target<=0) carry +1e30 in b.w — masked pairs lose the min.
// ---------------------------------------------------------------------------
__global__ __launch_bounds__(256, 4) void pair_min_kernel(
    const float* __restrict__ pred,
    const float* __restrict__ target,
    const float* __restrict__ P,
    float* __restrict__ pm12,
    float* __restrict__ pm21) {
    float fu = P[0], cu = P[2], p03 = P[3];
    float fv = P[5], cv = P[6], p13 = P[7], p23 = P[11];

    const float* __restrict__ dA;
    const float* __restrict__ dB;
    float* __restrict__ pm;
    if (blockIdx.z == 0) { dA = target; dB = pred;   pm = pm12; }
    else                 { dA = pred;   dB = target; pm = pm21; }

    __shared__ float4 sB[JLEN];
    int t = threadIdx.x;

    // B tile: one point per thread; validity always from target depth
    {
        int jb = blockIdx.y * JLEN + t;
        float db = dB[jb];
        float tb = target[jb];
        float inf_add = (tb > 0.0f) ? 0.0f : 1e30f;
        sB[t] = make_point(db, jb, fu, cu, p03, fv, cv, p13, p23, inf_add);
    }

    // A points: 8 per thread, fold -2 in
    int abase = blockIdx.x * ABLK + t;
    float ax[APT], ay[APT], az[APT], mn[APT];
    #pragma unroll
    for (int k = 0; k < APT; ++k) {
        int a = abase + k * 256;
        float da = dA[a];
        float4 pa = make_point(da, a, fu, cu, p03, fv, cv, p13, p23, 0.0f);
        ax[k] = -2.0f * pa.x;
        ay[k] = -2.0f * pa.y;
        az[k] = -2.0f * pa.z;
        mn[k] = 3e38f;
    }
    __syncthreads();

    #pragma unroll 2
    for (int j = 0; j < JLEN; j += 2) {
        float4 b0 = sB[j];
        float4 b1 = sB[j + 1];
        #pragma unroll
        for (int k = 0; k < APT; ++k) {
            float e0 = fmaf(ax[k], b0.x, fmaf(ay[k], b0.y, fmaf(az[k], b0.z, b0.w)));
            float e1 = fmaf(ax[k], b1.x, fmaf(ay[k], b1.y, fmaf(az[k], b1.z, b1.w)));
            mn[k] = fminf(mn[k], fminf(e0, e1)); // -> v_min3_f32
        }
    }

    int obase = blockIdx.y * NPIX + abase;
    #pragma unroll
    for (int k = 0; k < APT; ++k) pm[obase + k * 256] = mn[k];
}

// ---------------------------------------------------------------------------
// Reduce: 256 blocks. Each block owns 64 A-points; threads split the JC
// slices 4-way (min is exactly associative -> order-free), LDS-combine,
// add back |a|^2, masked sum with deterministic order.
// ---------------------------------------------------------------------------
__global__ __launch_bounds__(256) void reduce_kernel(
    const float* __restrict__ pm12,
    const float* __restrict__ pm21,
    const float* __restrict__ pred,
    const float* __restrict__ target,
    const float* __restrict__ P,
    float* __restrict__ bsum,
    float* __restrict__ bn) {
    int t = threadIdx.x;
    int al = t & 63, q = t >> 6;
    int a = blockIdx.x * 64 + al;

    float m12 = 3e38f, m21 = 3e38f;
    int jc0 = q * (JC / 4);
    for (int jc = jc0; jc < jc0 + JC / 4; ++jc) {
        m12 = fminf(m12, pm12[jc * NPIX + a]);
        m21 = fminf(m21, pm21[jc * NPIX + a]);
    }
    __shared__ float s12[4][64], s21[4][64];
    s12[q][al] = m12;
    s21[q][al] = m21;
    __syncthreads();

    if (t < 64) {
        m12 = fminf(fminf(s12[0][t], s12[1][t]), fminf(s12[2][t], s12[3][t]));
        m21 = fminf(fminf(s21[0][t], s21[1][t]), fminf(s21[2][t], s21[3][t]));

        float fu = P[0], cu = P[2], p03 = P[3];
        float fv = P[5], cv = P[6], p13 = P[7], p23 = P[11];
        float dt = target[a], dp = pred[a];
        float v = (dt > 0.0f) ? 1.0f : 0.0f;
        float4 pT = make_point(dt, a, fu, cu, p03, fv, cv, p13, p23, 0.0f);
        float4 pP = make_point(dp, a, fu, cu, p03, fv, cv, p13, p23, 0.0f);
        float contrib = v * ((m12 + pT.w) + (m21 + pP.w));

        for (int o = 32; o > 0; o >>= 1) {
            contrib += __shfl_down(contrib, o);
            v += __shfl_down(v, o);
        }
        if (t == 0) {
            bsum[blockIdx.x] = contrib;
            bn[blockIdx.x] = v;
        }
    }
}

// ---------------------------------------------------------------------------
// Final: fixed-order lane-parallel sum of 256 partials (deterministic).
// ---------------------------------------------------------------------------
__global__ void final_kernel(const float* __restrict__ bsum,
                             const float* __restrict__ bn,
                             float* __restrict__ out) {
    int t = threadIdx.x; // 64 threads
    float s = 0.0f, n = 0.0f;
    for (int i = t; i < 256; i += 64) { s += bsum[i]; n += bn[i]; }
    for (int o = 32; o > 0; o >>= 1) {
        s += __shfl_down(s, o);
        n += __shfl_down(n, o);
    }
    if (t == 0) out[0] = s / n;
}

extern "C" void kernel_launch(void* const* d_in, const int* in_sizes, int n_in,
                              void* d_out, int out_size, void* d_ws, size_t ws_size,
                              hipStream_t stream) {
    const float* pred   = (const float*)d_in[0];
    const float* target = (const float*)d_in[1];
    const float* P      = (const float*)d_in[2];
    float* out = (float*)d_out;

    char* ws = (char*)d_ws;
    float* pm12 = (float*)ws;                                  // JC*NPIX floats
    float* pm21 = pm12 + (size_t)JC * NPIX;
    float* bsum = pm21 + (size_t)JC * NPIX;                    // 256 floats
    float* bn   = bsum + 256;

    dim3 grid(NPIX / ABLK, JC, 2); // (8, 64, 2) = 1024 blocks
    pair_min_kernel<<<grid, 256, 0, stream>>>(pred, target, P, pm12, pm21);

    reduce_kernel<<<dim3(256), 256, 0, stream>>>(pm12, pm21, pred, target, P, bsum, bn);
    final_kernel<<<1, 64, 0, stream>>>(bsum, bn, out);
}